// Round 2
// baseline (2088.212 us; speedup 1.0000x reference)
//
#include <hip/hip_runtime.h>

typedef unsigned short ushort_t;
typedef __attribute__((ext_vector_type(8))) short short8;
typedef __attribute__((ext_vector_type(4))) float floatx4;

#define MFMA16x16x32(a, b, c) __builtin_amdgcn_mfma_f32_16x16x32_bf16(a, b, c, 0, 0, 0)

__device__ __forceinline__ float bf2f(ushort_t h) {
    unsigned int u = ((unsigned int)h) << 16;
    return __builtin_bit_cast(float, u);
}
__device__ __forceinline__ ushort_t f2bf(float f) {
    unsigned int u = __builtin_bit_cast(unsigned int, f);
    u += 0x7fffu + ((u >> 16) & 1u);
    return (ushort_t)(u >> 16);
}
__device__ __forceinline__ void gload_lds16(const ushort_t* g, ushort_t* l) {
    __builtin_amdgcn_global_load_lds(
        (const __attribute__((address_space(1))) unsigned int*)g,
        (__attribute__((address_space(3))) unsigned int*)l, 16, 0, 0);
}

// ---------------------------------------------------------------------------
// fp32 -> bf16 (RNE) conversion, 8 elems/thread, grid-stride.
// ---------------------------------------------------------------------------
__global__ __launch_bounds__(256) void conv_bf16(const float* __restrict__ in,
                                                 ushort_t* __restrict__ out, int n8) {
    int i = blockIdx.x * 256 + threadIdx.x;
    const int stride = gridDim.x * 256;
    for (; i < n8; i += stride) {
        const float* p = in + (size_t)i * 8;
        floatx4 a0 = *(const floatx4*)p;
        floatx4 a1 = *(const floatx4*)(p + 4);
        short8 o;
        o[0] = (short)f2bf(a0[0]); o[1] = (short)f2bf(a0[1]);
        o[2] = (short)f2bf(a0[2]); o[3] = (short)f2bf(a0[3]);
        o[4] = (short)f2bf(a1[0]); o[5] = (short)f2bf(a1[1]);
        o[6] = (short)f2bf(a1[2]); o[7] = (short)f2bf(a1[3]);
        *(short8*)(out + (size_t)i * 8) = o;
    }
}

// ---------------------------------------------------------------------------
// LayerNorm: one block per row of 2048. INF32=1: fp32 input (original x),
// INF32=0: bf16 input (x2 residual buffer). Params bf16, output bf16.
// ---------------------------------------------------------------------------
template <int INF32>
__global__ __launch_bounds__(256) void ln_kernel(const void* __restrict__ in,
                                                 const ushort_t* __restrict__ w,
                                                 const ushort_t* __restrict__ b,
                                                 ushort_t* __restrict__ out) {
    const int row = blockIdx.x;
    const int tid = threadIdx.x;
    const size_t base = (size_t)row * 2048 + (size_t)tid * 8;
    float v[8];
    if (INF32) {
        const float* p = (const float*)in + base;
        floatx4 a0 = *(const floatx4*)p;
        floatx4 a1 = *(const floatx4*)(p + 4);
        v[0] = a0[0]; v[1] = a0[1]; v[2] = a0[2]; v[3] = a0[3];
        v[4] = a1[0]; v[5] = a1[1]; v[6] = a1[2]; v[7] = a1[3];
    } else {
        short8 hv = *(const short8*)((const ushort_t*)in + base);
        const ushort_t* hp = (const ushort_t*)&hv;
#pragma unroll
        for (int k = 0; k < 8; k++) v[k] = bf2f(hp[k]);
    }
    float s = 0.f, sq = 0.f;
#pragma unroll
    for (int k = 0; k < 8; k++) { s += v[k]; sq += v[k] * v[k]; }
#pragma unroll
    for (int m = 32; m; m >>= 1) { s += __shfl_xor(s, m); sq += __shfl_xor(sq, m); }
    __shared__ float red[8];
    const int wv = tid >> 6;
    if ((tid & 63) == 0) { red[wv] = s; red[4 + wv] = sq; }
    __syncthreads();
    s = red[0] + red[1] + red[2] + red[3];
    sq = red[4] + red[5] + red[6] + red[7];
    const float mu = s * (1.f / 2048.f);
    const float var = fmaxf(sq * (1.f / 2048.f) - mu * mu, 0.f);
    const float rs = rsqrtf(var + 1e-5f);
    short8 ov;
#pragma unroll
    for (int k = 0; k < 8; k++) {
        const int c = tid * 8 + k;
        float y = (v[k] - mu) * rs * bf2f(w[c]) + bf2f(b[c]);
        ov[k] = (short)f2bf(y);
    }
    *(short8*)(out + base) = ov;
}

// ---------------------------------------------------------------------------
// GEMM: C[M,N] = A[M,K] * W[N,K]^T + bias (A,W,bias bf16), fused epilogues.
// m97 structure: 128x128 tile, BK=32, 256 thr (4 waves, 2x2 of 64x64),
// global_load_lds width-16 staging, 16x16x32 bf16 MFMA.
// EPI 0: +bias -> bf16 out                        (QKV)
// EPI 1: +bias +fp32 residual -> bf16 out         (attn out-proj -> x2)
// EPI 2: +bias, exact GELU -> bf16 out            (MLP up)
// EPI 3: +bias +bf16 residual -> FP32 out         (MLP down -> final output)
// ---------------------------------------------------------------------------
template <int EPI>
__global__ __launch_bounds__(256) void gemm_bt(const ushort_t* __restrict__ A,
                                               const ushort_t* __restrict__ W,
                                               const ushort_t* __restrict__ bias,
                                               const void* __restrict__ res,
                                               void* __restrict__ out,
                                               int M, int N, int K) {
    __shared__ ushort_t As[4096];  // [128][32]
    __shared__ ushort_t Bs[4096];  // [128][32]
    const int tid = threadIdx.x;
    const int lane = tid & 63;
    const int wave = tid >> 6;
    const int nbn = N >> 7;
    const int bm = blockIdx.x / nbn;
    const int bn = blockIdx.x % nbn;
    const int wm = (wave >> 1) * 64;
    const int wn = (wave & 1) * 64;
    const int la = lane & 15;
    const int qd = lane >> 4;

    floatx4 acc[4][4];
    const floatx4 z4 = {0.f, 0.f, 0.f, 0.f};
#pragma unroll
    for (int i = 0; i < 4; i++)
#pragma unroll
        for (int j = 0; j < 4; j++) acc[i][j] = z4;

    const ushort_t* ga = A + (size_t)(bm * 128 + (tid >> 2)) * K + (tid & 3) * 8;
    const ushort_t* gb = W + (size_t)(bn * 128 + (tid >> 2)) * K + (tid & 3) * 8;
    ushort_t* lA = As + (size_t)(tid & ~63) * 8;
    ushort_t* lB = Bs + (size_t)(tid & ~63) * 8;
    const size_t strideR = (size_t)64 * K;

    for (int kt = 0; kt < K; kt += 32) {
        __syncthreads();
        gload_lds16(ga + kt, lA);
        gload_lds16(ga + kt + strideR, lA + 2048);
        gload_lds16(gb + kt, lB);
        gload_lds16(gb + kt + strideR, lB + 2048);
        __syncthreads();
        short8 af[4], bfr[4];
#pragma unroll
        for (int i = 0; i < 4; i++) af[i] = *(const short8*)&As[(wm + i * 16 + la) * 32 + qd * 8];
#pragma unroll
        for (int j = 0; j < 4; j++) bfr[j] = *(const short8*)&Bs[(wn + j * 16 + la) * 32 + qd * 8];
#pragma unroll
        for (int i = 0; i < 4; i++)
#pragma unroll
            for (int j = 0; j < 4; j++) acc[i][j] = MFMA16x16x32(af[i], bfr[j], acc[i][j]);
    }

#pragma unroll
    for (int i = 0; i < 4; i++) {
#pragma unroll
        for (int j = 0; j < 4; j++) {
#pragma unroll
            for (int r = 0; r < 4; r++) {
                const int m = bm * 128 + wm + i * 16 + qd * 4 + r;
                const int n = bn * 128 + wn + j * 16 + la;
                const size_t idx = (size_t)m * N + n;
                float v = acc[i][j][r] + bf2f(bias[n]);
                if (EPI == 0) {
                    ((ushort_t*)out)[idx] = f2bf(v);
                } else if (EPI == 1) {
                    v += ((const float*)res)[idx];
                    ((ushort_t*)out)[idx] = f2bf(v);
                } else if (EPI == 2) {
                    v = 0.5f * v * (1.f + erff(v * 0.70710678118654752f));
                    ((ushort_t*)out)[idx] = f2bf(v);
                } else {
                    v += bf2f(((const ushort_t*)res)[idx]);
                    ((float*)out)[idx] = v;
                }
            }
        }
    }
}

// ---------------------------------------------------------------------------
// Flash attention with ALiBi + causal. One WG (256 thr) per (b, h, 64-row
// q-tile). 64-col K/V tiles. Each wave owns 16 q-rows. QK^T and PV via
// 16x16x32 bf16 MFMA; P round-trips through per-wave LDS; V stored transposed
// with XOR chunk swizzle. qkv layout: [B*S, 6144] rows = [q|k|v] bf16.
// ---------------------------------------------------------------------------
__global__ __launch_bounds__(256) void attn_kernel(const ushort_t* __restrict__ qkv,
                                                   const float* __restrict__ slopes,
                                                   ushort_t* __restrict__ out) {
    __shared__ ushort_t Qs[64 * 128];
    __shared__ ushort_t Ks[64 * 128];
    __shared__ ushort_t Vt[128 * 64];
    __shared__ ushort_t Ps[4 * 16 * 64];
    const int tid = threadIdx.x;
    const int lane = tid & 63;
    const int wave = tid >> 6;
    const int la = lane & 15;
    const int qd = lane >> 4;
    const int qt = blockIdx.x;
    const int h = blockIdx.y;
    const int b = blockIdx.z;
    const float slope = slopes[h];
    const float scale = 0.08838834764831845f;  // 1/sqrt(128)
    const size_t RS = 6144;

    const ushort_t* Qb = qkv + (size_t)b * 2048 * RS + h * 128;
    const ushort_t* Kb = Qb + 2048;
    const ushort_t* Vb = Qb + 4096;

    // Stage Q tile [64][128]; LDS slot (row, cs) holds global chunk cs^(row&15).
#pragma unroll
    for (int p = 0; p < 4; p++) {
        const int f = p * 256 + tid;
        const int r = f >> 4;
        const int cs = f & 15;
        gload_lds16(Qb + (size_t)(qt * 64 + r) * RS + (size_t)(cs ^ (r & 15)) * 8,
                    Qs + (size_t)(p * 256 + (tid & ~63)) * 8);
    }
    __syncthreads();
    short8 qa[4];
#pragma unroll
    for (int ks = 0; ks < 4; ks++)
        qa[ks] = *(const short8*)&Qs[(wave * 16 + la) * 128 + ((ks * 4 + qd) ^ la) * 8];

    floatx4 accO[8];
    const floatx4 z4 = {0.f, 0.f, 0.f, 0.f};
#pragma unroll
    for (int dt = 0; dt < 8; dt++) accO[dt] = z4;
    float mst[4] = {-1e30f, -1e30f, -1e30f, -1e30f};
    float lst[4] = {0.f, 0.f, 0.f, 0.f};

    for (int kt = 0; kt <= qt; kt++) {
        __syncthreads();  // prev iter finished reading Ks/Vt
#pragma unroll
        for (int p = 0; p < 4; p++) {
            const int f = p * 256 + tid;
            const int r = f >> 4;
            const int cs = f & 15;
            gload_lds16(Kb + (size_t)(kt * 64 + r) * RS + (size_t)(cs ^ (r & 15)) * 8,
                        Ks + (size_t)(p * 256 + (tid & ~63)) * 8);
        }
        // V transposed: Vt[d][k], k-chunks XOR-swizzled by (d&7); write order
        // rotated by lane to spread banks.
#pragma unroll
        for (int p = 0; p < 4; p++) {
            const int f = p * 256 + tid;
            const int r = f >> 4;          // k index 0..63
            const int c8 = (f & 15) * 8;   // d base
            short8 vv = *(const short8*)(Vb + (size_t)(kt * 64 + r) * RS + c8);
            const ushort_t* vs = (const ushort_t*)&vv;
            const int chunk = r >> 3;
            const int koff = r & 7;
#pragma unroll
            for (int s = 0; s < 8; s++) {
                const int i = (s + lane) & 7;
                const int d = c8 + i;
                Vt[d * 64 + (chunk ^ i) * 8 + koff] = vs[i];
            }
        }
        __syncthreads();

        // S = Q K^T (per wave: 16 rows x 64 cols)
        floatx4 sc[4];
#pragma unroll
        for (int nt = 0; nt < 4; nt++) sc[nt] = z4;
#pragma unroll
        for (int nt = 0; nt < 4; nt++) {
#pragma unroll
            for (int ks = 0; ks < 4; ks++) {
                short8 kb = *(const short8*)&Ks[(nt * 16 + la) * 128 + ((ks * 4 + qd) ^ la) * 8];
                sc[nt] = MFMA16x16x32(qa[ks], kb, sc[nt]);
            }
        }

        // Online softmax. Row of lane = qd*4 + r; col of lane = nt*16 + la.
        const int qmb = qt * 64 + wave * 16 + qd * 4;
        const int knb = kt * 64;
        float pb[4][4];
#pragma unroll
        for (int r = 0; r < 4; r++) {
            const int qm = qmb + r;
            float rmax = -1e30f;
#pragma unroll
            for (int nt = 0; nt < 4; nt++) {
                const int kn = knb + nt * 16 + la;
                float sval = sc[nt][r] * scale + slope * (float)(kn - qm);
                if (kn > qm) sval = -1e30f;
                pb[nt][r] = sval;
                rmax = fmaxf(rmax, sval);
            }
            rmax = fmaxf(rmax, __shfl_xor(rmax, 1));
            rmax = fmaxf(rmax, __shfl_xor(rmax, 2));
            rmax = fmaxf(rmax, __shfl_xor(rmax, 4));
            rmax = fmaxf(rmax, __shfl_xor(rmax, 8));
            const float mnew = fmaxf(mst[r], rmax);
            float rsum = 0.f;
#pragma unroll
            for (int nt = 0; nt < 4; nt++) {
                const float pv = __expf(pb[nt][r] - mnew);
                pb[nt][r] = pv;
                rsum += pv;
            }
            rsum += __shfl_xor(rsum, 1);
            rsum += __shfl_xor(rsum, 2);
            rsum += __shfl_xor(rsum, 4);
            rsum += __shfl_xor(rsum, 8);
            const float alpha = __expf(mst[r] - mnew);
            mst[r] = mnew;
            lst[r] = lst[r] * alpha + rsum;
#pragma unroll
            for (int dt = 0; dt < 8; dt++) accO[dt][r] *= alpha;
        }

        // P (C/D layout) -> per-wave LDS -> A-operand layout (same-wave only).
        ushort_t* Pw = Ps + wave * 1024;
#pragma unroll
        for (int r = 0; r < 4; r++)
#pragma unroll
            for (int nt = 0; nt < 4; nt++)
                Pw[(qd * 4 + r) * 64 + nt * 16 + la] = f2bf(pb[nt][r]);

        // O += P V
#pragma unroll
        for (int k2 = 0; k2 < 2; k2++) {
            short8 pa = *(const short8*)&Pw[la * 64 + k2 * 32 + qd * 8];
#pragma unroll
            for (int dt = 0; dt < 8; dt++) {
                const int d = dt * 16 + la;
                short8 vbf = *(const short8*)&Vt[d * 64 + ((k2 * 4 + qd) ^ (d & 7)) * 8];
                accO[dt] = MFMA16x16x32(pa, vbf, accO[dt]);
            }
        }
    }

    // Normalize and store [B*S, 2048] bf16
    const size_t orow0 = (size_t)b * 2048 + qt * 64 + wave * 16 + qd * 4;
#pragma unroll
    for (int r = 0; r < 4; r++) {
        const float inv = 1.f / lst[r];
#pragma unroll
        for (int dt = 0; dt < 8; dt++)
            out[(orow0 + r) * 2048 + h * 128 + dt * 16 + la] = f2bf(accO[dt][r] * inv);
    }
}

// ---------------------------------------------------------------------------
extern "C" void kernel_launch(void* const* d_in, const int* in_sizes, int n_in,
                              void* d_out, int out_size, void* d_ws, size_t ws_size,
                              hipStream_t stream) {
    (void)in_sizes; (void)n_in; (void)out_size; (void)ws_size;
    const float* x      = (const float*)d_in[0];
    const float* ln1w   = (const float*)d_in[1];
    const float* ln1b   = (const float*)d_in[2];
    const float* Wqkv   = (const float*)d_in[3];
    const float* bqkv   = (const float*)d_in[4];
    const float* Wo     = (const float*)d_in[5];
    const float* bo     = (const float*)d_in[6];
    const float* ln2w   = (const float*)d_in[7];
    const float* ln2b   = (const float*)d_in[8];
    const float* W1     = (const float*)d_in[9];
    const float* b1     = (const float*)d_in[10];
    const float* W2     = (const float*)d_in[11];
    const float* b2     = (const float*)d_in[12];
    const float* slopes = (const float*)d_in[13];
    float* outp = (float*)d_out;

    char* ws = (char*)d_ws;
    const size_t MB = 1ull << 20;
    // Workspace (~229 MB):
    //   [0,36MB)     wbuf    bf16, rotating big-weight region (Wqkv/Wo/W1/W2)
    //   [36,37MB)    small   bf16 vectors
    //   [37,69MB)    h_buf   bf16 [8192,2048]
    //   [69,197MB)   act     bf16: qkv [8192,6144] @+0, attn [8192,2048] @+96MB,
    //                              then act [8192,8192] @+0
    //   [197,229MB)  x2      bf16 [8192,2048]
    ushort_t* wbuf  = (ushort_t*)(ws);
    ushort_t* sv    = (ushort_t*)(ws + 36 * MB);
    ushort_t* ln1w_c = sv;            // 2048
    ushort_t* ln1b_c = sv + 2048;     // 2048
    ushort_t* bqkv_c = sv + 4096;     // 6144
    ushort_t* bo_c   = sv + 10240;    // 2048
    ushort_t* ln2w_c = sv + 12288;    // 2048
    ushort_t* ln2b_c = sv + 14336;    // 2048
    ushort_t* b1_c   = sv + 16384;    // 8192
    ushort_t* b2_c   = sv + 24576;    // 2048
    ushort_t* h_buf    = (ushort_t*)(ws + 37 * MB);
    ushort_t* qkv_buf  = (ushort_t*)(ws + 69 * MB);
    ushort_t* act_buf  = qkv_buf;
    ushort_t* attn_buf = (ushort_t*)(ws + 165 * MB);
    ushort_t* x2_buf   = (ushort_t*)(ws + 197 * MB);

    const int M = 8192;  // B*S

    // ---- LN1(x) -> h ----
    conv_bf16<<<8, 256, 0, stream>>>(ln1w, ln1w_c, 2048 / 8);
    conv_bf16<<<8, 256, 0, stream>>>(ln1b, ln1b_c, 2048 / 8);
    ln_kernel<1><<<M, 256, 0, stream>>>(x, ln1w_c, ln1b_c, h_buf);
    // ---- QKV GEMM ----
    conv_bf16<<<2048, 256, 0, stream>>>(Wqkv, wbuf, (6144 * 2048) / 8);
    conv_bf16<<<8, 256, 0, stream>>>(bqkv, bqkv_c, 6144 / 8);
    gemm_bt<0><<<(M / 128) * (6144 / 128), 256, 0, stream>>>(
        h_buf, wbuf, bqkv_c, nullptr, qkv_buf, M, 6144, 2048);
    // ---- Attention ----
    attn_kernel<<<dim3(32, 16, 4), 256, 0, stream>>>(qkv_buf, slopes, attn_buf);
    // ---- Out-proj + residual -> x2 (bf16) ----
    conv_bf16<<<1024, 256, 0, stream>>>(Wo, wbuf, (2048 * 2048) / 8);
    conv_bf16<<<8, 256, 0, stream>>>(bo, bo_c, 2048 / 8);
    gemm_bt<1><<<(M / 128) * (2048 / 128), 256, 0, stream>>>(
        attn_buf, wbuf, bo_c, x, x2_buf, M, 2048, 2048);
    // ---- LN2(x2) -> h ----
    conv_bf16<<<8, 256, 0, stream>>>(ln2w, ln2w_c, 2048 / 8);
    conv_bf16<<<8, 256, 0, stream>>>(ln2b, ln2b_c, 2048 / 8);
    ln_kernel<0><<<M, 256, 0, stream>>>(x2_buf, ln2w_c, ln2b_c, h_buf);
    // ---- MLP up + GELU ----
    conv_bf16<<<2048, 256, 0, stream>>>(W1, wbuf, (8192 * 2048) / 8);
    conv_bf16<<<8, 256, 0, stream>>>(b1, b1_c, 8192 / 8);
    gemm_bt<2><<<(M / 128) * (8192 / 128), 256, 0, stream>>>(
        h_buf, wbuf, b1_c, nullptr, act_buf, M, 8192, 2048);
    // ---- MLP down + residual -> out (fp32) ----
    conv_bf16<<<2048, 256, 0, stream>>>(W2, wbuf, (2048 * 8192) / 8);
    conv_bf16<<<8, 256, 0, stream>>>(b2, b2_c, 2048 / 8);
    gemm_bt<3><<<(M / 128) * (2048 / 128), 256, 0, stream>>>(
        act_buf, wbuf, b2_c, x2_buf, outp, M, 2048, 8192);
}